// Round 4
// baseline (638.913 us; speedup 1.0000x reference)
//
#include <hip/hip_runtime.h>

#define N_NODES 100000
#define N_EDGES 3200000
#define F_IN 128
#define F_OUT 16

#define GEMM_BLOCKS ((N_NODES + 15) / 16)   // 6250
#define CNT_BLOCKS  2048
#define SCAT_BLOCKS 2048
#define PULL_BLOCKS 2048
#define NPAD 100352                          // 98*1024, padded node count
#define NSCAN 98                             // scan blocks of 1024

// ---- ws layout (bytes) ----
#define OFF_CNT   0x000000u   // NPAD ints (zeroed)
#define OFF_WSI   0x080000u   // NPAD ints (zeroed): fixed-point weight sums (2^-20)
#define OFF_NPTR  0x100000u   // NPAD ints: run starts (stable)
#define OFF_CUR   0x180000u   // NPAD ints: scatter cursors (destroyed)
#define OFF_BSUM  0x1F0000u   // NSCAN ints
#define OFF_DINV  0x200000u   // N floats
#define OFF_HH    0x280000u   // N*16 floats (6.4 MB)
#define OFF_GG    0x900000u   // N*16 ushorts (3.2 MB), bf16
#define OFF_CSR   0x1000000u  // E int2 (25.6 MB), node-grouped (unsorted within run)
#define WS_NEEDED ((size_t)0x1000000 + (size_t)N_EDGES * 8)

__device__ __forceinline__ unsigned short f2bf(float f) {
    unsigned u = __float_as_uint(f);
    unsigned r = (u + 0x7FFFu + ((u >> 16) & 1u)) >> 16;   // RNE
    return (unsigned short)r;
}
__device__ __forceinline__ float bf2f(unsigned short v) {
    return __uint_as_float((unsigned)v << 16);
}

// ============ main path ============
// R3 lesson: LDS atomics are lane-serial (~200 cy per wave-op) -> 51.2M lane
// RMWs cost 270us. This pipeline has ZERO LDS atomics in hot loops; per-node
// aggregation is register-based (R0's proven pull), and the node-grouped CSR
// is built with native global int atomics (L2-parallel).

// K0: zero cnt + wsum_i regions (1 MB)
__global__ void k_zero(int4* __restrict__ p) {
    p[blockIdx.x * 256 + threadIdx.x] = make_int4(0, 0, 0, 0);
}

// K1: per-node edge counts (global fire-and-forget int atomics) + h = x@W
__global__ void k_count_gemm(const int* __restrict__ col,
                             int* __restrict__ cnt,
                             const float* __restrict__ x,
                             const float* __restrict__ W,
                             float* __restrict__ h) {
    int tid = threadIdx.x;
    if (blockIdx.x < CNT_BLOCKS) {
        int t0 = blockIdx.x * 256 + tid;
        for (int e = t0; e < N_EDGES; e += CNT_BLOCKS * 256)
            atomicAdd(&cnt[col[e]], 1);        // global_atomic_add, no return
    } else {
        __shared__ float Ws[F_IN * F_OUT];
        for (int i = tid; i < F_IN * F_OUT; i += 256) Ws[i] = W[i];
        __syncthreads();
        int n = (blockIdx.x - CNT_BLOCKS) * 16 + (tid >> 4);
        int j = tid & 15;
        if (n >= N_NODES) return;
        const float4* xr = (const float4*)(x + (size_t)n * F_IN);
        float acc = 0.0f;
#pragma unroll
        for (int k4 = 0; k4 < F_IN / 4; ++k4) {
            float4 xv = xr[k4];
            int k = k4 * 4;
            acc += xv.x * Ws[(k + 0) * F_OUT + j];
            acc += xv.y * Ws[(k + 1) * F_OUT + j];
            acc += xv.z * Ws[(k + 2) * F_OUT + j];
            acc += xv.w * Ws[(k + 3) * F_OUT + j];
        }
        h[(size_t)n * F_OUT + j] = acc;
    }
}

// K2: per-1024-chunk reduction of cnt -> bsum[98]
__global__ void k_scan_red(const int* __restrict__ cnt, int* __restrict__ bsum) {
    __shared__ int sw[4];
    int tid = threadIdx.x;
    int4 v = ((const int4*)cnt)[blockIdx.x * 256 + tid];
    int s = v.x + v.y + v.z + v.w;
#pragma unroll
    for (int o = 32; o >= 1; o >>= 1) s += __shfl_down(s, o);
    if ((tid & 63) == 0) sw[tid >> 6] = s;
    __syncthreads();
    if (tid == 0) bsum[blockIdx.x] = sw[0] + sw[1] + sw[2] + sw[3];
}

// K3: exclusive scan: each block scans bsum for its base, then its own 1024
// counts; writes nodeptr (stable) and cursor (consumed by k_scatter).
__global__ void k_scan_add(const int* __restrict__ cnt, const int* __restrict__ bsum,
                           int* __restrict__ nodeptr, int* __restrict__ cursor) {
    __shared__ int sb[128];
    __shared__ int sw[4];
    int tid = threadIdx.x;
    if (tid < 128) sb[tid] = (tid < NSCAN) ? bsum[tid] : 0;
    __syncthreads();
    for (int off = 1; off < 128; off <<= 1) {
        int t = (tid < 128 && tid >= off) ? sb[tid - off] : 0;
        __syncthreads();
        if (tid < 128) sb[tid] += t;
        __syncthreads();
    }
    int b = blockIdx.x;
    int base = (b == 0) ? 0 : sb[b - 1];

    int4 v = ((const int4*)cnt)[b * 256 + tid];
    int ts = v.x + v.y + v.z + v.w;
    int l = tid & 63, w = tid >> 6;
    int inc = ts;
#pragma unroll
    for (int off = 1; off < 64; off <<= 1) {
        int t = __shfl_up(inc, off);
        if (l >= off) inc += t;
    }
    if (l == 63) sw[w] = inc;
    __syncthreads();
    int woff = 0;
    for (int k = 0; k < 4; ++k) if (k < w) woff += sw[k];
    int exc = base + woff + inc - ts;
    int4 o;
    o.x = exc;
    o.y = o.x + v.x;
    o.z = o.y + v.y;
    o.w = o.z + v.z;
    ((int4*)nodeptr)[b * 256 + tid] = o;
    ((int4*)cursor)[b * 256 + tid] = o;
}

// K4: scatter edges to node-grouped csr via cursor ret-atomics; accumulate
// fixed-point weight sums (int atomic, no return). Order within run: any.
__global__ void k_scatter(const int* __restrict__ row, const int* __restrict__ col,
                          const float* __restrict__ ew,
                          int* __restrict__ cursor, int* __restrict__ wsum_i,
                          int2* __restrict__ csr) {
    int t0 = blockIdx.x * 256 + threadIdx.x;
    for (int e = t0; e < N_EDGES; e += SCAT_BLOCKS * 256) {
        int c = col[e];
        int r = row[e];
        float w = ew[e];
        atomicAdd(&wsum_i[c], __float2int_rn(w * 1048576.0f));  // 2^20 fixed point
        int pos = atomicAdd(&cursor[c], 1);                     // ret-atomic
        csr[pos] = make_int2(r, __float_as_int(w));
    }
}

// K5: streaming — dinv = rsqrt(1 + wsum*2^-20); gb = bf16(dinv * h)
__global__ void k_prep2(const int* __restrict__ wsum_i, const float* __restrict__ h,
                        float* __restrict__ dinv, unsigned short* __restrict__ gb) {
    int i = blockIdx.x * 256 + threadIdx.x;
    if (i >= N_NODES * F_OUT) return;
    int n = i >> 4;
    float d = rsqrtf(1.0f + (float)wsum_i[n] * (1.0f / 1048576.0f));
    if ((i & 15) == 0) dinv[n] = d;
    gb[i] = f2bf(d * h[i]);
}

// K6: persistent pull — wave per node, register accumulation, zero atomics.
__global__ void k_pull3(const int* __restrict__ nodeptr, const int* __restrict__ cnt,
                        const int2* __restrict__ csr, const unsigned short* __restrict__ gb,
                        const float* __restrict__ dinv, const float* __restrict__ bias,
                        float* __restrict__ out) {
    int wid = threadIdx.x >> 6;
    int lane = threadIdx.x & 63;
    int s = lane >> 4;
    int j = lane & 15;
    float bj = bias[j];
    for (int q = blockIdx.x; q < (N_NODES + 3) / 4; q += PULL_BLOCKS) {
        int n = q * 4 + wid;
        if (n >= N_NODES) continue;
        int p0 = nodeptr[n];
        int c = cnt[n];
        float acc = 0.0f;
#pragma unroll 4
        for (int i = s; i < c; i += 4) {
            int2 rec = csr[p0 + i];     // 16-lane broadcast
            acc += bf2f(gb[(size_t)rec.x * F_OUT + j]) * __int_as_float(rec.y);
        }
        acc += __shfl_xor(acc, 16);
        acc += __shfl_xor(acc, 32);
        if (s == 0) {
            float d = dinv[n];
            float gs = bf2f(gb[(size_t)n * F_OUT + j]);   // self-loop term
            out[(size_t)n * F_OUT + j] = bj + d * (gs + acc);
        }
    }
}

// ============ fallback path (proven; fp32 g) ============

#define EDGE_BLOCKS_FB ((N_EDGES + 255) / 256)
__global__ void k_init_fb(float* __restrict__ deg) {
    int i = blockIdx.x * blockDim.x + threadIdx.x;
    if (i < N_NODES) deg[i] = 1.0f;
}
__global__ void k_fused_fb(const int* __restrict__ col, const float* __restrict__ ew,
                           float* __restrict__ deg, const float* __restrict__ x,
                           const float* __restrict__ W, float* __restrict__ h) {
    int b3 = blockIdx.x / 3;
    int r3 = blockIdx.x % 3;
    if (r3 < 2) {
        int e = (b3 * 2 + r3) * 256 + threadIdx.x;
        if (e < N_EDGES) atomicAdd(&deg[col[e]], ew[e]);
    } else {
        __shared__ float Ws[F_IN * F_OUT];
        int tid = threadIdx.x;
        for (int i = tid; i < F_IN * F_OUT; i += 256) Ws[i] = W[i];
        __syncthreads();
        int n = b3 * 16 + (tid >> 4);
        int j = tid & 15;
        if (n >= N_NODES) return;
        const float4* xr = (const float4*)(x + (size_t)n * F_IN);
        float acc = 0.0f;
#pragma unroll
        for (int k4 = 0; k4 < F_IN / 4; ++k4) {
            float4 xv = xr[k4];
            int k = k4 * 4;
            acc += xv.x * Ws[(k + 0) * F_OUT + j];
            acc += xv.y * Ws[(k + 1) * F_OUT + j];
            acc += xv.z * Ws[(k + 2) * F_OUT + j];
            acc += xv.w * Ws[(k + 3) * F_OUT + j];
        }
        h[(size_t)n * F_OUT + j] = acc;
    }
}
__global__ void k_final_fb(float* __restrict__ deg, const float* __restrict__ h,
                           const float* __restrict__ b, float* __restrict__ g,
                           float* __restrict__ out) {
    int i = blockIdx.x * blockDim.x + threadIdx.x;
    int n = i >> 4;
    int j = i & 15;
    if (n >= N_NODES) return;
    float d = rsqrtf(deg[n]);
    if (j == 0) deg[n] = d;
    float gg = d * h[i];
    g[i] = gg;
    out[i] = b[j] + d * gg;
}
__global__ void k_scatter_fb(const int* __restrict__ row, const int* __restrict__ col,
                             const float* __restrict__ ew, const float* __restrict__ dinv,
                             const float* __restrict__ g, float* __restrict__ out) {
    long long tid = (long long)blockIdx.x * blockDim.x + threadIdx.x;
    int e = (int)(tid >> 4);
    int j = (int)(tid & 15);
    if (e >= N_EDGES) return;
    int c = col[e];
    float norm = ew[e] * dinv[c];
    atomicAdd(&out[(size_t)c * F_OUT + j], g[(size_t)row[e] * F_OUT + j] * norm);
}

extern "C" void kernel_launch(void* const* d_in, const int* in_sizes, int n_in,
                              void* d_out, int out_size, void* d_ws, size_t ws_size,
                              hipStream_t stream) {
    const float* x  = (const float*)d_in[0];
    const int*   ei = (const int*)d_in[1];   // [2, N_EDGES] int32
    const float* ew = (const float*)d_in[2];
    const float* W  = (const float*)d_in[3];
    const float* b  = (const float*)d_in[4];
    float* out = (float*)d_out;

    const int* row = ei;            // edge_index[0] = source
    const int* col = ei + N_EDGES;  // edge_index[1] = destination

    char* ws = (char*)d_ws;
    dim3 blk(256);

    if (ws_size >= WS_NEEDED) {
        int*   cnt  = (int*)(ws + OFF_CNT);
        int*   wsi  = (int*)(ws + OFF_WSI);
        int*   nptr = (int*)(ws + OFF_NPTR);
        int*   cur  = (int*)(ws + OFF_CUR);
        int*   bsum = (int*)(ws + OFF_BSUM);
        float* dinv = (float*)(ws + OFF_DINV);
        float* h    = (float*)(ws + OFF_HH);
        unsigned short* gb = (unsigned short*)(ws + OFF_GG);
        int2*  csr  = (int2*)(ws + OFF_CSR);

        k_zero<<<256, blk, 0, stream>>>((int4*)ws);            // cnt + wsi (1 MB)
        k_count_gemm<<<CNT_BLOCKS + GEMM_BLOCKS, blk, 0, stream>>>(col, cnt, x, W, h);
        k_scan_red<<<NSCAN, blk, 0, stream>>>(cnt, bsum);
        k_scan_add<<<NSCAN, blk, 0, stream>>>(cnt, bsum, nptr, cur);
        k_scatter<<<SCAT_BLOCKS, blk, 0, stream>>>(row, col, ew, cur, wsi, csr);
        k_prep2<<<(N_NODES * F_OUT + 255) / 256, blk, 0, stream>>>(wsi, h, dinv, gb);
        k_pull3<<<PULL_BLOCKS, blk, 0, stream>>>(nptr, cnt, csr, gb, dinv, b, out);
    } else {
        float* deg = (float*)ws;
        float* h   = (float*)(ws + (1u << 20));
        float* g   = (float*)(ws + (8u << 20));
        k_init_fb<<<(N_NODES + 255) / 256, blk, 0, stream>>>(deg);
        k_fused_fb<<<EDGE_BLOCKS_FB + GEMM_BLOCKS, blk, 0, stream>>>(col, ew, deg, x, W, h);
        k_final_fb<<<(N_NODES * F_OUT + 255) / 256, blk, 0, stream>>>(deg, h, b, g, out);
        long long total = (long long)N_EDGES * F_OUT;
        k_scatter_fb<<<(unsigned)((total + 255) / 256), blk, 0, stream>>>(row, col, ew, deg, g, out);
    }
}

// Round 5
// 247.147 us; speedup vs baseline: 2.5852x; 2.5852x over previous
//
#include <hip/hip_runtime.h>

#define N_NODES 100000
#define N_EDGES 3200000
#define F_IN 128
#define F_OUT 16

#define NSEG 512                 // binning segments
#define EPS (N_EDGES / NSEG)     // 6250 edges/segment (exact)
#define NBUCK 512                // destination buckets
#define NPB 196                  // nodes per bucket: 196*512 = 100352 >= N
#define CAPR 7424                // bucket capacity (mean 6250, +15 sigma)
#define GEMM_BLOCKS ((N_NODES + 15) / 16)   // 6250
#define PULL_BLOCKS 2048

// ---- ws layout (bytes) ---- (WS_NEEDED kept EXACTLY at R0's formula so the
// main-path trigger is unchanged; csr region ends at 40.0MB <= 40.4MB granted)
#define OFF_CUR   0x000000u   // NBUCK ints: bucket cursors, init bk*CAPR
#define OFF_NPTR  0x010000u   // N ints: per-node run start (absolute csr idx)
#define OFF_NCNT  0x080000u   // N ints: per-node run length
#define OFF_DINV  0x0F0000u   // N floats
#define OFF_HH    0x160000u   // N*16 floats (6.4 MB)
#define OFF_GG    0x780000u   // N*16 ushorts (3.2 MB), bf16
#define OFF_CSR   0xB00000u   // NBUCK*CAPR int2 (30.4 MB), bucket regions
#define WS_NEEDED ((size_t)0x1000000 + (size_t)N_EDGES * 8)

__device__ __forceinline__ unsigned short f2bf(float f) {
    unsigned u = __float_as_uint(f);
    unsigned r = (u + 0x7FFFu + ((u >> 16) & 1u)) >> 16;   // RNE
    return (unsigned short)r;
}
__device__ __forceinline__ float bf2f(unsigned short v) {
    return __uint_as_float((unsigned)v << 16);
}

// ============ main path ============
// R3 lesson: LDS atomics are lane-serial (~5.3us per M lane-ops) -> no
// per-(record x feature) atomics anywhere. R4 lesson: scattered 8B global
// writes from random XCDs get ~12x write-amplified -> all csr writes are
// LDS-staged and written linearly by a single block.

// K1: h = x@W (proven block shape); last block inits bucket cursors.
__global__ void k_gemm(const float* __restrict__ x, const float* __restrict__ W,
                       float* __restrict__ h, int* __restrict__ cursor) {
    int tid = threadIdx.x;
    if (blockIdx.x == GEMM_BLOCKS) {
        cursor[tid] = tid * CAPR;
        cursor[tid + 256] = (tid + 256) * CAPR;
        return;
    }
    __shared__ float Ws[F_IN * F_OUT];
    for (int i = tid; i < F_IN * F_OUT; i += 256) Ws[i] = W[i];
    __syncthreads();
    int n = blockIdx.x * 16 + (tid >> 4);
    int j = tid & 15;
    if (n >= N_NODES) return;
    const float4* xr = (const float4*)(x + (size_t)n * F_IN);
    float acc = 0.0f;
#pragma unroll
    for (int k4 = 0; k4 < F_IN / 4; ++k4) {
        float4 xv = xr[k4];
        int k = k4 * 4;
        acc += xv.x * Ws[(k + 0) * F_OUT + j];
        acc += xv.y * Ws[(k + 1) * F_OUT + j];
        acc += xv.z * Ws[(k + 2) * F_OUT + j];
        acc += xv.w * Ws[(k + 3) * F_OUT + j];
    }
    h[(size_t)n * F_OUT + j] = acc;
}

// K2: per-segment bucket binning. Hist -> wave-scan + global bucket-space
// reservation (1 ret-atomic per bucket per segment) -> rank into LDS
// (+ per-slot bucket byte) -> linear write-out (no binary search).
__global__ void __launch_bounds__(512) k_bin2(const int* __restrict__ row,
                                              const int* __restrict__ col,
                                              const float* __restrict__ ew,
                                              int* __restrict__ cursor,
                                              int2* __restrict__ csr) {
    __shared__ int2 srec[EPS];             // 50000 B
    __shared__ unsigned char sbk[EPS];     // 6250 B
    __shared__ int lcnt[NBUCK];            // hist, then rank counters
    __shared__ int lpre[NBUCK];            // exclusive prefix
    __shared__ int gofs[NBUCK];            // global base - lpre
    __shared__ int wtot[8];
    int tid = threadIdx.x;
    int e0 = blockIdx.x * EPS;

    lcnt[tid] = 0;
    __syncthreads();
    for (int i = tid; i < EPS; i += 512)
        atomicAdd(&lcnt[col[e0 + i] / NPB], 1);
    __syncthreads();

    // 512-entry exclusive scan: 8 wave scans + cross-wave fixup (2 barriers)
    int v = lcnt[tid];
    int inc = v;
#pragma unroll
    for (int off = 1; off < 64; off <<= 1) {
        int t = __shfl_up(inc, off);
        if ((tid & 63) >= off) inc += t;
    }
    if ((tid & 63) == 63) wtot[tid >> 6] = inc;
    __syncthreads();
    int woff = 0;
#pragma unroll
    for (int k = 0; k < 8; ++k)
        if (k < (tid >> 6)) woff += wtot[k];
    int excl = woff + inc - v;
    lpre[tid] = excl;
    int gstart = atomicAdd(&cursor[tid], v);   // reserve bucket space
    gofs[tid] = gstart - excl;
    lcnt[tid] = excl;                          // rank counters
    __syncthreads();

    for (int i = tid; i < EPS; i += 512) {
        int e = e0 + i;
        int r = row[e];
        int c = col[e];
        int bk = c / NPB;
        int pos = atomicAdd(&lcnt[bk], 1);     // native LDS int atomic
        srec[pos] = make_int2((r << 8) | (c - bk * NPB), __float_as_int(ew[e]));
        sbk[pos] = (unsigned char)bk;
    }
    __syncthreads();

    int mid = lpre[256];                       // first slot of buckets >=256
    for (int t = tid; t < EPS; t += 512) {
        int bk = sbk[t] + ((t >= mid) ? 256 : 0);
        csr[gofs[bk] + t] = srec[t];           // coalesced bucket-run writes
    }
}

// K3: per-bucket counting sort (stage -> hist -> scan -> rank-rewrite),
// nodeptr/ncnt, then per-node serial weight-sum over the L2-hot sorted run,
// dinv = rsqrt(wsum), gb = bf16(dinv*h).
__global__ void __launch_bounds__(256) k_sort2(const int* __restrict__ cursor,
                                               int2* __restrict__ csr,
                                               const float* __restrict__ h,
                                               float* __restrict__ dinv,
                                               unsigned short* __restrict__ gb,
                                               int* __restrict__ nodeptr,
                                               int* __restrict__ ncnt) {
    __shared__ int2 srec[CAPR];                // 59392 B
    __shared__ int cnt[256];
    __shared__ int cur[256];
    __shared__ int wtot[4];
    float* dl = (float*)cnt;                   // reuse after scan
    int tid = threadIdx.x;
    int b = blockIdx.x;
    int c0 = b * NPB;
    int rb = b * CAPR;
    int total = cursor[b] - rb;
    if (total > CAPR) total = CAPR;            // statistically unreachable

    cnt[tid] = 0;
    __syncthreads();
    for (int i = tid; i < total; i += 256) {
        int2 rec = csr[rb + i];
        srec[i] = rec;
        atomicAdd(&cnt[rec.x & 255], 1);
    }
    __syncthreads();

    int v = cnt[tid];
    int inc = v;
#pragma unroll
    for (int off = 1; off < 64; off <<= 1) {
        int t = __shfl_up(inc, off);
        if ((tid & 63) >= off) inc += t;
    }
    if ((tid & 63) == 63) wtot[tid >> 6] = inc;
    __syncthreads();
    int woff = 0;
#pragma unroll
    for (int k = 0; k < 4; ++k)
        if (k < (tid >> 6)) woff += wtot[k];
    int excl = woff + inc - v;
    int n = c0 + tid;
    if (tid < NPB && n < N_NODES) {
        nodeptr[n] = rb + excl;
        ncnt[n] = v;
    }
    cur[tid] = excl;
    __syncthreads();

    for (int i = tid; i < total; i += 256) {
        int2 rec = srec[i];
        int pos = atomicAdd(&cur[rec.x & 255], 1);
        csr[rb + pos] = make_int2(rec.x >> 8, rec.y);   // plain src id now
    }
    __syncthreads();   // drains vmem before re-read (compiler waitcnt+barrier)

    float d = 0.0f;
    if (tid < NPB && n < N_NODES) {
        float s = 1.0f;                         // self-loop weight
        const int2* run = csr + rb + excl;
        for (int k = 0; k < v; ++k) s += __int_as_float(run[k].y);
        d = rsqrtf(s);
        dinv[n] = d;
    }
    __syncthreads();                            // cnt dead; safe to reuse as dl
    dl[tid] = d;
    __syncthreads();
    for (int i = tid; i < NPB * F_OUT; i += 256) {
        int idx = c0 * F_OUT + i;
        if (idx < N_NODES * F_OUT) gb[idx] = f2bf(dl[i >> 4] * h[idx]);
    }
}

// K4: pull, wave per node. Lane-per-record coalesced csr loads (512B/wave),
// 16 per-lane feature accumulators from two dwordx4 gathers of the
// L2-resident bf16 g-table, fold-reduction (lane l4 ends holding feature
// bitrev4(l4)), epilogue adds self-term + bias.
__global__ void __launch_bounds__(256) k_pull4(const int* __restrict__ nodeptr,
                                               const int* __restrict__ ncnt,
                                               const int2* __restrict__ csr,
                                               const unsigned short* __restrict__ gb,
                                               const float* __restrict__ dinv,
                                               const float* __restrict__ bias,
                                               float* __restrict__ out) {
    int wid = threadIdx.x >> 6;
    int lane = threadIdx.x & 63;
    int l4 = lane & 15;
    int fr = ((l4 & 1) << 3) | ((l4 & 2) << 1) | ((l4 & 4) >> 1) | ((l4 & 8) >> 3);
    float bj = bias[fr];
    for (int n = blockIdx.x * 4 + wid; n < N_NODES; n += PULL_BLOCKS * 4) {
        int p0 = nodeptr[n];
        int c = ncnt[n];
        float acc[16];
#pragma unroll
        for (int k = 0; k < 16; ++k) acc[k] = 0.0f;
        for (int base = 0; base < c; base += 64) {
            int i = base + lane;
            int2 rec = (i < c) ? csr[p0 + i] : make_int2(0, 0);  // w=0 pads
            float w = __int_as_float(rec.y);
            const uint4* gr = (const uint4*)(gb + ((size_t)rec.x << 4));
            uint4 qa = gr[0];
            uint4 qb = gr[1];
            acc[0]  += w * __uint_as_float(qa.x << 16);
            acc[1]  += w * __uint_as_float(qa.x & 0xFFFF0000u);
            acc[2]  += w * __uint_as_float(qa.y << 16);
            acc[3]  += w * __uint_as_float(qa.y & 0xFFFF0000u);
            acc[4]  += w * __uint_as_float(qa.z << 16);
            acc[5]  += w * __uint_as_float(qa.z & 0xFFFF0000u);
            acc[6]  += w * __uint_as_float(qa.w << 16);
            acc[7]  += w * __uint_as_float(qa.w & 0xFFFF0000u);
            acc[8]  += w * __uint_as_float(qb.x << 16);
            acc[9]  += w * __uint_as_float(qb.x & 0xFFFF0000u);
            acc[10] += w * __uint_as_float(qb.y << 16);
            acc[11] += w * __uint_as_float(qb.y & 0xFFFF0000u);
            acc[12] += w * __uint_as_float(qb.z << 16);
            acc[13] += w * __uint_as_float(qb.z & 0xFFFF0000u);
            acc[14] += w * __uint_as_float(qb.w << 16);
            acc[15] += w * __uint_as_float(qb.w & 0xFFFF0000u);
        }
        // fold-reduce: halve acc count per butterfly step
        bool b1 = (lane & 1) != 0;
#pragma unroll
        for (int k = 0; k < 8; ++k) {
            float keep = b1 ? acc[k + 8] : acc[k];
            float send = b1 ? acc[k] : acc[k + 8];
            acc[k] = keep + __shfl_xor(send, 1);
        }
        bool b2 = (lane & 2) != 0;
#pragma unroll
        for (int k = 0; k < 4; ++k) {
            float keep = b2 ? acc[k + 4] : acc[k];
            float send = b2 ? acc[k] : acc[k + 4];
            acc[k] = keep + __shfl_xor(send, 2);
        }
        bool b4 = (lane & 4) != 0;
#pragma unroll
        for (int k = 0; k < 2; ++k) {
            float keep = b4 ? acc[k + 2] : acc[k];
            float send = b4 ? acc[k] : acc[k + 2];
            acc[k] = keep + __shfl_xor(send, 4);
        }
        bool b8 = (lane & 8) != 0;
        {
            float keep = b8 ? acc[1] : acc[0];
            float send = b8 ? acc[0] : acc[1];
            acc[0] = keep + __shfl_xor(send, 8);
        }
        acc[0] += __shfl_xor(acc[0], 16);
        acc[0] += __shfl_xor(acc[0], 32);
        if (lane < 16) {
            float d = dinv[n];
            float gs = bf2f(gb[(size_t)n * F_OUT + fr]);
            out[(size_t)n * F_OUT + fr] = bj + d * (gs + acc[0]);
        }
    }
}

// ============ fallback path (proven; fp32 g) ============

#define EDGE_BLOCKS_FB ((N_EDGES + 255) / 256)
__global__ void k_init_fb(float* __restrict__ deg) {
    int i = blockIdx.x * blockDim.x + threadIdx.x;
    if (i < N_NODES) deg[i] = 1.0f;
}
__global__ void k_fused_fb(const int* __restrict__ col, const float* __restrict__ ew,
                           float* __restrict__ deg, const float* __restrict__ x,
                           const float* __restrict__ W, float* __restrict__ h) {
    int b3 = blockIdx.x / 3;
    int r3 = blockIdx.x % 3;
    if (r3 < 2) {
        int e = (b3 * 2 + r3) * 256 + threadIdx.x;
        if (e < N_EDGES) atomicAdd(&deg[col[e]], ew[e]);
    } else {
        __shared__ float Ws[F_IN * F_OUT];
        int tid = threadIdx.x;
        for (int i = tid; i < F_IN * F_OUT; i += 256) Ws[i] = W[i];
        __syncthreads();
        int n = b3 * 16 + (tid >> 4);
        int j = tid & 15;
        if (n >= N_NODES) return;
        const float4* xr = (const float4*)(x + (size_t)n * F_IN);
        float acc = 0.0f;
#pragma unroll
        for (int k4 = 0; k4 < F_IN / 4; ++k4) {
            float4 xv = xr[k4];
            int k = k4 * 4;
            acc += xv.x * Ws[(k + 0) * F_OUT + j];
            acc += xv.y * Ws[(k + 1) * F_OUT + j];
            acc += xv.z * Ws[(k + 2) * F_OUT + j];
            acc += xv.w * Ws[(k + 3) * F_OUT + j];
        }
        h[(size_t)n * F_OUT + j] = acc;
    }
}
__global__ void k_final_fb(float* __restrict__ deg, const float* __restrict__ h,
                           const float* __restrict__ b, float* __restrict__ g,
                           float* __restrict__ out) {
    int i = blockIdx.x * blockDim.x + threadIdx.x;
    int n = i >> 4;
    int j = i & 15;
    if (n >= N_NODES) return;
    float d = rsqrtf(deg[n]);
    if (j == 0) deg[n] = d;
    float gg = d * h[i];
    g[i] = gg;
    out[i] = b[j] + d * gg;
}
__global__ void k_scatter_fb(const int* __restrict__ row, const int* __restrict__ col,
                             const float* __restrict__ ew, const float* __restrict__ dinv,
                             const float* __restrict__ g, float* __restrict__ out) {
    long long tid = (long long)blockIdx.x * blockDim.x + threadIdx.x;
    int e = (int)(tid >> 4);
    int j = (int)(tid & 15);
    if (e >= N_EDGES) return;
    int c = col[e];
    float norm = ew[e] * dinv[c];
    atomicAdd(&out[(size_t)c * F_OUT + j], g[(size_t)row[e] * F_OUT + j] * norm);
}

extern "C" void kernel_launch(void* const* d_in, const int* in_sizes, int n_in,
                              void* d_out, int out_size, void* d_ws, size_t ws_size,
                              hipStream_t stream) {
    const float* x  = (const float*)d_in[0];
    const int*   ei = (const int*)d_in[1];   // [2, N_EDGES] int32
    const float* ew = (const float*)d_in[2];
    const float* W  = (const float*)d_in[3];
    const float* b  = (const float*)d_in[4];
    float* out = (float*)d_out;

    const int* row = ei;            // edge_index[0] = source
    const int* col = ei + N_EDGES;  // edge_index[1] = destination

    char* ws = (char*)d_ws;
    dim3 blk(256);

    if (ws_size >= WS_NEEDED) {
        int*   cur  = (int*)(ws + OFF_CUR);
        int*   nptr = (int*)(ws + OFF_NPTR);
        int*   ncnt = (int*)(ws + OFF_NCNT);
        float* dinv = (float*)(ws + OFF_DINV);
        float* h    = (float*)(ws + OFF_HH);
        unsigned short* gb = (unsigned short*)(ws + OFF_GG);
        int2*  csr  = (int2*)(ws + OFF_CSR);

        k_gemm<<<GEMM_BLOCKS + 1, blk, 0, stream>>>(x, W, h, cur);
        k_bin2<<<NSEG, 512, 0, stream>>>(row, col, ew, cur, csr);
        k_sort2<<<NBUCK, blk, 0, stream>>>(cur, csr, h, dinv, gb, nptr, ncnt);
        k_pull4<<<PULL_BLOCKS, blk, 0, stream>>>(nptr, ncnt, csr, gb, dinv, b, out);
    } else {
        float* deg = (float*)ws;
        float* h   = (float*)(ws + (1u << 20));
        float* g   = (float*)(ws + (8u << 20));
        k_init_fb<<<(N_NODES + 255) / 256, blk, 0, stream>>>(deg);
        k_fused_fb<<<EDGE_BLOCKS_FB + GEMM_BLOCKS, blk, 0, stream>>>(col, ew, deg, x, W, h);
        k_final_fb<<<(N_NODES * F_OUT + 255) / 256, blk, 0, stream>>>(deg, h, b, g, out);
        long long total = (long long)N_EDGES * F_OUT;
        k_scatter_fb<<<(unsigned)((total + 255) / 256), blk, 0, stream>>>(row, col, ew, deg, g, out);
    }
}

// Round 6
// 239.420 us; speedup vs baseline: 2.6686x; 1.0323x over previous
//
#include <hip/hip_runtime.h>

#define N_NODES 100000
#define N_EDGES 3200000
#define F_IN 128
#define F_OUT 16

#define NSEG 512                 // binning segments
#define EPS (N_EDGES / NSEG)     // 6250 edges/segment (exact)
#define EPT 13                   // max edges per thread (ceil(6250/512))
#define NBUCK 512                // destination buckets
#define NPB 196                  // nodes per bucket: 196*512 = 100352 >= N
#define CAPR 7424                // bucket capacity (mean 6250, +15 sigma)
#define GEMM32 ((N_NODES + 31) / 32)        // 3125 gemm blocks (512 thr)
#define PULL_BLOCKS 2048

// ---- ws layout (bytes) ----
#define OFF_CUR   0x000000u   // NBUCK ints: bucket fill counts (memset 0)
#define OFF_NPTR  0x010000u   // N ints: per-node run start (absolute csr idx)
#define OFF_NCNT  0x080000u   // N ints: per-node run length
#define OFF_DINV  0x0F0000u   // N floats
#define OFF_HH    0x160000u   // N*16 floats (6.4 MB)
#define OFF_GG    0x780000u   // N*16 ushorts (3.2 MB), bf16
#define OFF_CSR   0xB00000u   // NBUCK*CAPR int2 (29 MiB), bucket regions
#define WS_NEEDED ((size_t)0x1000000 + (size_t)N_EDGES * 8)

__device__ __forceinline__ unsigned short f2bf(float f) {
    unsigned u = __float_as_uint(f);
    unsigned r = (u + 0x7FFFu + ((u >> 16) & 1u)) >> 16;   // RNE
    return (unsigned short)r;
}
__device__ __forceinline__ float bf2f(unsigned short v) {
    return __uint_as_float((unsigned)v << 16);
}

// ============ main path ============
// R3: LDS atomics are lane-serial (~3.24 cy/lane-op) -> minimize per-edge
// atomic count (now 1 per edge per kernel). R4: scattered 8B stores from
// random XCDs get write-amplified -> keep (block,bucket) chunks contiguous.

// K1: merged binning + GEMM.
//  blocks [0,NSEG): register-staged edges; ONE LDS ret-atomic per edge gives
//  rank AND (post-pass) count; global per-bucket reservation; direct global
//  write csr[gofs[bk]+pos]. No LDS record staging, no scan.
//  blocks [NSEG,..): h = x@W, 32 nodes per 512-thread block.
__global__ void __launch_bounds__(512) k_binA(const int* __restrict__ row,
                                              const int* __restrict__ col,
                                              const float* __restrict__ ew,
                                              int* __restrict__ cursor,
                                              int2* __restrict__ csr,
                                              const float* __restrict__ x,
                                              const float* __restrict__ W,
                                              float* __restrict__ h) {
    __shared__ int smem[2048];      // bin: lcnt[512]+gofs[512] | gemm: Ws 8KB
    int tid = threadIdx.x;
    if (blockIdx.x < NSEG) {
        int* lcnt = smem;
        int* gofs = smem + 512;
        int e0 = blockIdx.x * EPS;
        lcnt[tid] = 0;
        __syncthreads();

        int2 rec[EPT];
        int meta[EPT];
#pragma unroll
        for (int k = 0; k < EPT; ++k) {
            int i = k * 512 + tid;
            if (k < EPT - 1 || i < EPS) {
                int e = e0 + i;
                int r = row[e];
                int c = col[e];
                float w = ew[e];
                int bk = c / NPB;
                int pos = atomicAdd(&lcnt[bk], 1);          // native, ret
                rec[k] = make_int2((r << 8) | (c - bk * NPB), __float_as_int(w));
                meta[k] = (bk << 16) | pos;
            }
        }
        __syncthreads();

        int v = lcnt[tid];
        gofs[tid] = tid * CAPR + atomicAdd(&cursor[tid], v);  // global reserve
        __syncthreads();

#pragma unroll
        for (int k = 0; k < EPT; ++k) {
            int i = k * 512 + tid;
            if (k < EPT - 1 || i < EPS) {
                int m = meta[k];
                csr[gofs[m >> 16] + (m & 0xFFFF)] = rec[k];
            }
        }
    } else {
        float* Ws = (float*)smem;
        for (int i = tid; i < F_IN * F_OUT; i += 512) Ws[i] = W[i];
        __syncthreads();
        int n = (blockIdx.x - NSEG) * 32 + (tid >> 4);
        int j = tid & 15;
        if (n >= N_NODES) return;
        const float4* xr = (const float4*)(x + (size_t)n * F_IN);
        float acc = 0.0f;
#pragma unroll
        for (int k4 = 0; k4 < F_IN / 4; ++k4) {
            float4 xv = xr[k4];
            int k = k4 * 4;
            acc += xv.x * Ws[(k + 0) * F_OUT + j];
            acc += xv.y * Ws[(k + 1) * F_OUT + j];
            acc += xv.z * Ws[(k + 2) * F_OUT + j];
            acc += xv.w * Ws[(k + 3) * F_OUT + j];
        }
        h[(size_t)n * F_OUT + j] = acc;
    }
}

// K2: per-bucket counting sort. ONE LDS ret-atomic per edge (rank saved in
// spos); wave-scan -> node bases; rank-rewrite (no atomics); per-node serial
// weight-sum over L2-hot run; dinv; gb = bf16(dinv*h).
__global__ void __launch_bounds__(256) k_sortA(const int* __restrict__ cursor,
                                               int2* __restrict__ csr,
                                               const float* __restrict__ h,
                                               float* __restrict__ dinv,
                                               unsigned short* __restrict__ gb,
                                               int* __restrict__ nodeptr,
                                               int* __restrict__ ncnt) {
    __shared__ int2 srec[CAPR];                 // 59392 B
    __shared__ unsigned short spos[CAPR];       // 14848 B
    __shared__ int cnt[256];
    __shared__ int basel[256];
    __shared__ int wtot[4];
    __shared__ float dl[256];
    int tid = threadIdx.x;
    int b = blockIdx.x;
    int c0 = b * NPB;
    int rb = b * CAPR;
    int total = cursor[b];
    if (total > CAPR) total = CAPR;             // statistically unreachable

    cnt[tid] = 0;
    __syncthreads();
    for (int i = tid; i < total; i += 256) {
        int2 rec = csr[rb + i];
        srec[i] = rec;
        spos[i] = (unsigned short)atomicAdd(&cnt[rec.x & 255], 1);
    }
    __syncthreads();

    int v = cnt[tid];
    int inc = v;
#pragma unroll
    for (int off = 1; off < 64; off <<= 1) {
        int t = __shfl_up(inc, off);
        if ((tid & 63) >= off) inc += t;
    }
    if ((tid & 63) == 63) wtot[tid >> 6] = inc;
    __syncthreads();
    int woff = 0;
#pragma unroll
    for (int k = 0; k < 4; ++k)
        if (k < (tid >> 6)) woff += wtot[k];
    int excl = woff + inc - v;
    int n = c0 + tid;
    if (tid < NPB && n < N_NODES) {
        nodeptr[n] = rb + excl;
        ncnt[n] = v;
    }
    basel[tid] = excl;
    __syncthreads();

    for (int i = tid; i < total; i += 256) {
        int2 rec = srec[i];
        int p = basel[rec.x & 255] + spos[i];
        csr[rb + p] = make_int2(rec.x >> 8, rec.y);   // plain src id now
    }
    __syncthreads();   // vmcnt(0) drained before barrier -> rewrite visible

    float d = 0.0f;
    if (tid < NPB && n < N_NODES) {
        float s = 1.0f;                         // self-loop weight
        const int2* run = csr + rb + excl;
        for (int k = 0; k < v; ++k) s += __int_as_float(run[k].y);
        d = rsqrtf(s);
        dinv[n] = d;
    }
    dl[tid] = d;
    __syncthreads();
    for (int i = tid; i < NPB * F_OUT; i += 256) {
        int idx = c0 * F_OUT + i;
        if (idx < N_NODES * F_OUT) gb[idx] = f2bf(dl[i >> 4] * h[idx]);
    }
}

// K3: pull, wave per node. Lane-per-record coalesced csr loads (512B/wave),
// 16 per-lane feature accumulators from two dwordx4 gathers of the
// L2-resident bf16 g-table, fold-reduction (lane l4 ends holding feature
// bitrev4(l4)), epilogue adds self-term + bias.
__global__ void __launch_bounds__(256) k_pull4(const int* __restrict__ nodeptr,
                                               const int* __restrict__ ncnt,
                                               const int2* __restrict__ csr,
                                               const unsigned short* __restrict__ gb,
                                               const float* __restrict__ dinv,
                                               const float* __restrict__ bias,
                                               float* __restrict__ out) {
    int wid = threadIdx.x >> 6;
    int lane = threadIdx.x & 63;
    int l4 = lane & 15;
    int fr = ((l4 & 1) << 3) | ((l4 & 2) << 1) | ((l4 & 4) >> 1) | ((l4 & 8) >> 3);
    float bj = bias[fr];
    for (int n = blockIdx.x * 4 + wid; n < N_NODES; n += PULL_BLOCKS * 4) {
        int p0 = nodeptr[n];
        int c = ncnt[n];
        float acc[16];
#pragma unroll
        for (int k = 0; k < 16; ++k) acc[k] = 0.0f;
        for (int base = 0; base < c; base += 64) {
            int i = base + lane;
            int2 rec = (i < c) ? csr[p0 + i] : make_int2(0, 0);  // w=0 pads
            float w = __int_as_float(rec.y);
            const uint4* gr = (const uint4*)(gb + ((size_t)rec.x << 4));
            uint4 qa = gr[0];
            uint4 qb = gr[1];
            acc[0]  += w * __uint_as_float(qa.x << 16);
            acc[1]  += w * __uint_as_float(qa.x & 0xFFFF0000u);
            acc[2]  += w * __uint_as_float(qa.y << 16);
            acc[3]  += w * __uint_as_float(qa.y & 0xFFFF0000u);
            acc[4]  += w * __uint_as_float(qa.z << 16);
            acc[5]  += w * __uint_as_float(qa.z & 0xFFFF0000u);
            acc[6]  += w * __uint_as_float(qa.w << 16);
            acc[7]  += w * __uint_as_float(qa.w & 0xFFFF0000u);
            acc[8]  += w * __uint_as_float(qb.x << 16);
            acc[9]  += w * __uint_as_float(qb.x & 0xFFFF0000u);
            acc[10] += w * __uint_as_float(qb.y << 16);
            acc[11] += w * __uint_as_float(qb.y & 0xFFFF0000u);
            acc[12] += w * __uint_as_float(qb.z << 16);
            acc[13] += w * __uint_as_float(qb.z & 0xFFFF0000u);
            acc[14] += w * __uint_as_float(qb.w << 16);
            acc[15] += w * __uint_as_float(qb.w & 0xFFFF0000u);
        }
        // fold-reduce: halve acc count per butterfly step
        bool b1 = (lane & 1) != 0;
#pragma unroll
        for (int k = 0; k < 8; ++k) {
            float keep = b1 ? acc[k + 8] : acc[k];
            float send = b1 ? acc[k] : acc[k + 8];
            acc[k] = keep + __shfl_xor(send, 1);
        }
        bool b2 = (lane & 2) != 0;
#pragma unroll
        for (int k = 0; k < 4; ++k) {
            float keep = b2 ? acc[k + 4] : acc[k];
            float send = b2 ? acc[k] : acc[k + 4];
            acc[k] = keep + __shfl_xor(send, 2);
        }
        bool b4 = (lane & 4) != 0;
#pragma unroll
        for (int k = 0; k < 2; ++k) {
            float keep = b4 ? acc[k + 2] : acc[k];
            float send = b4 ? acc[k] : acc[k + 2];
            acc[k] = keep + __shfl_xor(send, 4);
        }
        bool b8 = (lane & 8) != 0;
        {
            float keep = b8 ? acc[1] : acc[0];
            float send = b8 ? acc[0] : acc[1];
            acc[0] = keep + __shfl_xor(send, 8);
        }
        acc[0] += __shfl_xor(acc[0], 16);
        acc[0] += __shfl_xor(acc[0], 32);
        if (lane < 16) {
            float d = dinv[n];
            float gs = bf2f(gb[(size_t)n * F_OUT + fr]);
            out[(size_t)n * F_OUT + fr] = bj + d * (gs + acc[0]);
        }
    }
}

// ============ fallback path (proven; fp32 g) ============

#define EDGE_BLOCKS_FB ((N_EDGES + 255) / 256)
#define GEMM_BLOCKS_FB ((N_NODES + 15) / 16)
__global__ void k_init_fb(float* __restrict__ deg) {
    int i = blockIdx.x * blockDim.x + threadIdx.x;
    if (i < N_NODES) deg[i] = 1.0f;
}
__global__ void k_fused_fb(const int* __restrict__ col, const float* __restrict__ ew,
                           float* __restrict__ deg, const float* __restrict__ x,
                           const float* __restrict__ W, float* __restrict__ h) {
    int b3 = blockIdx.x / 3;
    int r3 = blockIdx.x % 3;
    if (r3 < 2) {
        int e = (b3 * 2 + r3) * 256 + threadIdx.x;
        if (e < N_EDGES) atomicAdd(&deg[col[e]], ew[e]);
    } else {
        __shared__ float Ws[F_IN * F_OUT];
        int tid = threadIdx.x;
        for (int i = tid; i < F_IN * F_OUT; i += 256) Ws[i] = W[i];
        __syncthreads();
        int n = b3 * 16 + (tid >> 4);
        int j = tid & 15;
        if (n >= N_NODES) return;
        const float4* xr = (const float4*)(x + (size_t)n * F_IN);
        float acc = 0.0f;
#pragma unroll
        for (int k4 = 0; k4 < F_IN / 4; ++k4) {
            float4 xv = xr[k4];
            int k = k4 * 4;
            acc += xv.x * Ws[(k + 0) * F_OUT + j];
            acc += xv.y * Ws[(k + 1) * F_OUT + j];
            acc += xv.z * Ws[(k + 2) * F_OUT + j];
            acc += xv.w * Ws[(k + 3) * F_OUT + j];
        }
        h[(size_t)n * F_OUT + j] = acc;
    }
}
__global__ void k_final_fb(float* __restrict__ deg, const float* __restrict__ h,
                           const float* __restrict__ b, float* __restrict__ g,
                           float* __restrict__ out) {
    int i = blockIdx.x * blockDim.x + threadIdx.x;
    int n = i >> 4;
    int j = i & 15;
    if (n >= N_NODES) return;
    float d = rsqrtf(deg[n]);
    if (j == 0) deg[n] = d;
    float gg = d * h[i];
    g[i] = gg;
    out[i] = b[j] + d * gg;
}
__global__ void k_scatter_fb(const int* __restrict__ row, const int* __restrict__ col,
                             const float* __restrict__ ew, const float* __restrict__ dinv,
                             const float* __restrict__ g, float* __restrict__ out) {
    long long tid = (long long)blockIdx.x * blockDim.x + threadIdx.x;
    int e = (int)(tid >> 4);
    int j = (int)(tid & 15);
    if (e >= N_EDGES) return;
    int c = col[e];
    float norm = ew[e] * dinv[c];
    atomicAdd(&out[(size_t)c * F_OUT + j], g[(size_t)row[e] * F_OUT + j] * norm);
}

extern "C" void kernel_launch(void* const* d_in, const int* in_sizes, int n_in,
                              void* d_out, int out_size, void* d_ws, size_t ws_size,
                              hipStream_t stream) {
    const float* x  = (const float*)d_in[0];
    const int*   ei = (const int*)d_in[1];   // [2, N_EDGES] int32
    const float* ew = (const float*)d_in[2];
    const float* W  = (const float*)d_in[3];
    const float* b  = (const float*)d_in[4];
    float* out = (float*)d_out;

    const int* row = ei;            // edge_index[0] = source
    const int* col = ei + N_EDGES;  // edge_index[1] = destination

    char* ws = (char*)d_ws;
    dim3 blk(256);

    if (ws_size >= WS_NEEDED) {
        int*   cur  = (int*)(ws + OFF_CUR);
        int*   nptr = (int*)(ws + OFF_NPTR);
        int*   ncnt = (int*)(ws + OFF_NCNT);
        float* dinv = (float*)(ws + OFF_DINV);
        float* h    = (float*)(ws + OFF_HH);
        unsigned short* gb = (unsigned short*)(ws + OFF_GG);
        int2*  csr  = (int2*)(ws + OFF_CSR);

        hipMemsetAsync(cur, 0, NBUCK * sizeof(int), stream);
        k_binA<<<NSEG + GEMM32, 512, 0, stream>>>(row, col, ew, cur, csr, x, W, h);
        k_sortA<<<NBUCK, blk, 0, stream>>>(cur, csr, h, dinv, gb, nptr, ncnt);
        k_pull4<<<PULL_BLOCKS, blk, 0, stream>>>(nptr, ncnt, csr, gb, dinv, b, out);
    } else {
        float* deg = (float*)ws;
        float* h   = (float*)(ws + (1u << 20));
        float* g   = (float*)(ws + (8u << 20));
        k_init_fb<<<(N_NODES + 255) / 256, blk, 0, stream>>>(deg);
        k_fused_fb<<<EDGE_BLOCKS_FB + GEMM_BLOCKS_FB, blk, 0, stream>>>(col, ew, deg, x, W, h);
        k_final_fb<<<(N_NODES * F_OUT + 255) / 256, blk, 0, stream>>>(deg, h, b, g, out);
        long long total = (long long)N_EDGES * F_OUT;
        k_scatter_fb<<<(unsigned)((total + 255) / 256), blk, 0, stream>>>(row, col, ew, deg, g, out);
    }
}